// Round 1
// baseline (2879.999 us; speedup 1.0000x reference)
//
#include <hip/hip_runtime.h>

// Problem constants
#define N_NODES 100000
#define HDIM    64
#define R_REL   3
#define E_EDGES 800000
#define L_EDGES 200000
#define NT      (N_NODES/16)   // 6250 node tiles of 16
#define GB      1024           // gru blocks (per relation)
#define ABPR    391            // att blocks per relation

// dst-binned scatter parameters
#define TS      128            // dst nodes per bin
#define NB      782            // ceil(N/TS)
#define BCAP    2048           // slot capacity per bin (mean 1023, ~32 sigma margin)
#define NBP     800            // padded per-relation stride of binCur
#define RCH     8192           // edges per reorder block
#define RB      98             // ceil(E/RCH)

typedef short s16x8 __attribute__((ext_vector_type(8)));
typedef float f32x4 __attribute__((ext_vector_type(4)));
typedef unsigned short u16;

__device__ __forceinline__ u16 f2bf(float f){
    union { float f; unsigned int i; } v; v.f = f;
    unsigned int u = v.i + 0x7FFFu + ((v.i >> 16) & 1u);   // RNE
    return (u16)(u >> 16);
}
__device__ __forceinline__ s16x8 packbf(float4 a, float4 b){
    s16x8 r;
    r[0]=(short)f2bf(a.x); r[1]=(short)f2bf(a.y); r[2]=(short)f2bf(a.z); r[3]=(short)f2bf(a.w);
    r[4]=(short)f2bf(b.x); r[5]=(short)f2bf(b.y); r[6]=(short)f2bf(b.z); r[7]=(short)f2bf(b.w);
    return r;
}
__device__ __forceinline__ s16x8 ldpack(const float* p){   // 8 consecutive f32 -> bf16x8
    return packbf(*(const float4*)p, *(const float4*)(p + 4));
}
__device__ __forceinline__ f32x4 mfma16(s16x8 a, s16x8 b, f32x4 c){
    return __builtin_amdgcn_mfma_f32_16x16x32_bf16(a, b, c, 0, 0, 0);
}
__device__ __forceinline__ float fsigm(float x){
    x = fmaxf(-30.f, fminf(30.f, x));
    return 1.f/(1.f + __expf(-x));
}
__device__ __forceinline__ float ftanh(float x){
    x = fminf(15.f, fmaxf(-15.f, x));
    float e = __expf(2.f*x);
    return (e-1.f)/(e+1.f);
}

// ---- init per-bin cursors: binCur[r*NBP + b] = b*BCAP (positions relative to sorted_r) ----
__global__ __launch_bounds__(256) void k_init(int* __restrict__ binCur)
{
    int i = blockIdx.x*256 + threadIdx.x;
    if (i < 3*NBP) binCur[i] = (i % NBP) * BCAP;
}

// ---- counting-sort edges of one relation into dst-bins (LDS-aggregated reservation) ----
__global__ __launch_bounds__(256) void k_reorder(const int* __restrict__ ei_r,
        int* __restrict__ binCur, unsigned int* __restrict__ sorted)
{
    __shared__ int h[NB];
    const int* dst = ei_r + E_EDGES;
    int tid = threadIdx.x;
    int e0 = blockIdx.x * RCH;
    int e1 = (e0 + RCH < E_EDGES) ? e0 + RCH : E_EDGES;

    for (int i = tid; i < NB; i += 256) h[i] = 0;
    __syncthreads();
    // count this block's edges per bin
    for (int e = e0 + tid; e < e1; e += 256)
        atomicAdd(&h[dst[e] >> 7], 1);
    __syncthreads();
    // reserve a contiguous chunk per touched bin; h[bin] becomes the absolute base
    for (int i = tid; i < NB; i += 256){
        int c = h[i];
        if (c) h[i] = atomicAdd(&binCur[i], c);
    }
    __syncthreads();
    // distribute: LDS atomic gives absolute slot directly
    for (int e = e0 + tid; e < e1; e += 256){
        int d = dst[e];
        int bin = d >> 7;
        int pos = atomicAdd(&h[bin], 1);
        sorted[pos] = (unsigned)ei_r[e] | ((unsigned)(d & 127) << 17);
    }
}

// ---- binned scatter (LDS accumulate) fused with dense:
//      h = relu(segsum(x[src]) @ Wr.T + br + xin @ Wo.T)   (f32 out) ----
__global__ __launch_bounds__(256) void k_binfused(
        const unsigned int* __restrict__ sorted, const int* __restrict__ binCur,
        const float* __restrict__ xin,
        const float* __restrict__ Wr, const float* __restrict__ br,
        const float* __restrict__ Wo, float* __restrict__ hbuf)
{
    __shared__ float tile[TS*64];          // 32 KB
    int b = blockIdx.x;
    int tid = threadIdx.x;
    int w = tid >> 6, lane = tid & 63;

    {   // zero the tile (8 float4 per thread)
        float4 z4 = {0.f,0.f,0.f,0.f};
        float4* t4 = (float4*)tile;
        #pragma unroll
        for (int i = 0; i < (TS*64/4)/256; ++i) t4[tid + i*256] = z4;
    }
    __syncthreads();

    // scatter phase: each wave takes chunks of 8 edges; 8 gathers in flight
    int i0 = b*BCAP;
    int i1 = binCur[b];
    for (int i = i0 + w*8; i < i1; i += 32){
        if (i + 8 <= i1){
            unsigned pk[8]; float v[8];
            #pragma unroll
            for (int u = 0; u < 8; ++u) pk[u] = sorted[i+u];
            #pragma unroll
            for (int u = 0; u < 8; ++u) v[u] = xin[(size_t)(pk[u] & 0x1FFFFu)*64 + lane];
            #pragma unroll
            for (int u = 0; u < 8; ++u) atomicAdd(&tile[(pk[u] >> 17)*64 + lane], v[u]);
        } else {
            for (int e = i; e < i1; ++e){
                unsigned pk = sorted[e];
                float v = xin[(size_t)(pk & 0x1FFFFu)*64 + lane];
                atomicAdd(&tile[(pk >> 17)*64 + lane], v);
            }
        }
    }
    __syncthreads();

    // dense phase (same MFMA layout as the proven k_dense, A from LDS tile)
    int col = lane & 15, quad = lane >> 4, k0 = quad*8;
    s16x8 fr[4][2], fo[4][2];
    float bias[4];
    #pragma unroll
    for (int c = 0; c < 4; ++c){
        int m = c*16 + col;
        fr[c][0] = ldpack(Wr + m*64 + k0);
        fr[c][1] = ldpack(Wr + m*64 + 32 + k0);
        fo[c][0] = ldpack(Wo + m*64 + k0);
        fo[c][1] = ldpack(Wo + m*64 + 32 + k0);
        bias[c]  = br[m];
    }
    #pragma unroll
    for (int st = 0; st < 2; ++st){
        int s = st*4 + w;                       // subtile 0..7 (16 nodes each)
        int nodeBase = b*TS + s*16;
        if (nodeBase < N_NODES){
            const float* arow = tile + (s*16 + col)*64;
            s16x8 a1h0 = ldpack(arow + k0);
            s16x8 a1h1 = ldpack(arow + 32 + k0);
            int node = nodeBase + col;
            s16x8 a2h0 = ldpack(xin + (size_t)node*64 + k0);
            s16x8 a2h1 = ldpack(xin + (size_t)node*64 + 32 + k0);
            #pragma unroll
            for (int c = 0; c < 4; ++c){
                f32x4 acc = {0.f,0.f,0.f,0.f};
                acc = mfma16(a1h0, fr[c][0], acc);
                acc = mfma16(a1h1, fr[c][1], acc);
                acc = mfma16(a2h0, fo[c][0], acc);
                acc = mfma16(a2h1, fo[c][1], acc);
                #pragma unroll
                for (int ii = 0; ii < 4; ++ii){
                    int row = nodeBase + quad*4 + ii;
                    float vv = acc[ii] + bias[c];
                    hbuf[(size_t)row*64 + c*16 + col] = vv > 0.f ? vv : 0.f;
                }
            }
        }
    }
}

// ---- GRU (one relation), all f32. hbuf MAY ALIAS cur: barrier after loads.
__global__ __launch_bounds__(256) void k_gru(const float* hbuf, const float* past,
        const float* __restrict__ Wi, const float* __restrict__ Wh,
        const float* __restrict__ bi_, const float* __restrict__ bh_, float* cur)
{
    int w = threadIdx.x >> 6, lane = threadIdx.x & 63;
    int col = lane & 15, quad = lane >> 4, k0 = quad*8;

    s16x8 fwi[3][2], fwh[3][2];
    float vbi[3], vbh[3];
    #pragma unroll
    for (int g = 0; g < 3; ++g){
        int m = g*64 + w*16 + col;
        fwi[g][0] = ldpack(Wi + m*64 + k0);
        fwi[g][1] = ldpack(Wi + m*64 + 32 + k0);
        fwh[g][0] = ldpack(Wh + m*64 + k0);
        fwh[g][1] = ldpack(Wh + m*64 + 32 + k0);
        vbi[g] = bi_[m]; vbh[g] = bh_[m];
    }
    int j = w*16 + col;
    for (int t = blockIdx.x; t < NT; t += GB){
        int node = t*16 + col;
        const float* hrow = hbuf + (size_t)node*64;
        const float* prow = past + (size_t)node*64;
        s16x8 ah0 = ldpack(hrow + k0);
        s16x8 ah1 = ldpack(hrow + 32 + k0);
        s16x8 ap0 = ldpack(prow + k0);
        s16x8 ap1 = ldpack(prow + 32 + k0);
        float pv[4];
        #pragma unroll
        for (int i = 0; i < 4; ++i)
            pv[i] = past[(size_t)(t*16 + quad*4 + i)*64 + j];
        // all waves must finish reading h[t] before any wave overwrites cur[t]
        __syncthreads();
        f32x4 gi[3], gh[3];
        #pragma unroll
        for (int g = 0; g < 3; ++g){
            f32x4 z0 = {0.f,0.f,0.f,0.f};
            gi[g] = mfma16(ah1, fwi[g][1], mfma16(ah0, fwi[g][0], z0));
            gh[g] = mfma16(ap1, fwh[g][1], mfma16(ap0, fwh[g][0], z0));
        }
        #pragma unroll
        for (int i = 0; i < 4; ++i){
            int row = t*16 + quad*4 + i;
            float ir = gi[0][i]+vbi[0], iz = gi[1][i]+vbi[1], in_ = gi[2][i]+vbi[2];
            float hr = gh[0][i]+vbh[0], hz = gh[1][i]+vbh[1], hn = gh[2][i]+vbh[2];
            float rg = fsigm(ir + hr);
            float zg = fsigm(iz + hz);
            float ng = ftanh(in_ + rg*hn);
            cur[(size_t)row*64 + j] = (1.f - zg)*ng + zg*pv[i];
        }
    }
}

// ---- attention score (all rels) ----
__global__ __launch_bounds__(256) void k_att(const float* __restrict__ cur,
        const float* __restrict__ kW, const float* __restrict__ kb,
        const float* __restrict__ q, float* __restrict__ scoreOut)
{
    int r  = blockIdx.x / ABPR;
    int bi = blockIdx.x % ABPR;
    int w = threadIdx.x >> 6, lane = threadIdx.x & 63;
    int col = lane & 15, quad = lane >> 4, k0 = quad*8;

    s16x8 fk[4][2];
    float vkb[4], vq[4];
    #pragma unroll
    for (int c = 0; c < 4; ++c){
        int m = c*16 + col;
        fk[c][0] = ldpack(kW + m*64 + k0);
        fk[c][1] = ldpack(kW + m*64 + 32 + k0);
        vkb[c] = kb[m]; vq[c] = q[m];
    }
    float p = 0.f;
    int wid = bi*4 + w;
    for (int t = wid; t < NT; t += ABPR*4){
        int node = t*16 + col;
        const float* crow = cur + ((size_t)r*N_NODES + node)*64;
        s16x8 a0 = ldpack(crow + k0);
        s16x8 a1 = ldpack(crow + 32 + k0);
        #pragma unroll
        for (int c = 0; c < 4; ++c){
            f32x4 acc = {0.f,0.f,0.f,0.f};
            acc = mfma16(a1, fk[c][1], mfma16(a0, fk[c][0], acc));
            #pragma unroll
            for (int i = 0; i < 4; ++i)
                p += ftanh(acc[i] + vkb[c]) * vq[c];
        }
    }
    #pragma unroll
    for (int o = 32; o; o >>= 1) p += __shfl_xor(p, o, 64);
    if (lane == 0) unsafeAtomicAdd(scoreOut + r, p);
}

// ---- combine1: aggsem(f32) = sum_r softmax(score)[r] * cur[r] ----
__global__ __launch_bounds__(256) void k_combine1(const float* __restrict__ scoreS,
        const float* __restrict__ cur, float* __restrict__ aggsem)
{
    float s0 = scoreS[0]*(1.f/N_NODES), s1 = scoreS[1]*(1.f/N_NODES), s2 = scoreS[2]*(1.f/N_NODES);
    float mx = fmaxf(s0, fmaxf(s1, s2));
    float e0 = __expf(s0-mx), e1 = __expf(s1-mx), e2 = __expf(s2-mx);
    float inv = 1.f/(e0+e1+e2);
    float a0 = e0*inv, a1 = e1*inv, a2 = e2*inv;

    size_t idx = (size_t)blockIdx.x*blockDim.x + threadIdx.x;   // one thread = 4 elems
    const size_t S = (size_t)N_NODES*64;
    float4 v0 = *(const float4*)(cur + idx*4);
    float4 v1 = *(const float4*)(cur + S + idx*4);
    float4 v2 = *(const float4*)(cur + 2*S + idx*4);
    float4 o;
    o.x = a0*v0.x + a1*v1.x + a2*v2.x;
    o.y = a0*v0.y + a1*v1.y + a2*v2.y;
    o.z = a0*v0.z + a1*v1.z + a2*v2.z;
    o.w = a0*v0.w + a1*v1.w + a2*v2.w;
    *(float4*)(aggsem + idx*4) = o;
}

// ---- combine2 + z ----
__global__ __launch_bounds__(256) void k_combine2z(const float* __restrict__ scoreS,
        const float* __restrict__ cur2, const float* __restrict__ postW,
        const float* __restrict__ postb, float* __restrict__ z)
{
    float s0 = scoreS[0]*(1.f/N_NODES), s1 = scoreS[1]*(1.f/N_NODES), s2 = scoreS[2]*(1.f/N_NODES);
    float mx = fmaxf(s0, fmaxf(s1, s2));
    float e0 = __expf(s0-mx), e1 = __expf(s1-mx), e2 = __expf(s2-mx);
    float inv = 1.f/(e0+e1+e2);
    float a0 = e0*inv, a1 = e1*inv, a2 = e2*inv;

    int wid = (int)((blockIdx.x*blockDim.x + threadIdx.x) >> 6);  // node
    int lane = threadIdx.x & 63;
    const size_t S = (size_t)N_NODES*64;
    size_t o = (size_t)wid*64 + lane;
    float v = a0*cur2[o] + a1*cur2[S + o] + a2*cur2[2*S + o];
    float p0 = v * postW[lane];
    float p1 = v * postW[64 + lane];
    #pragma unroll
    for (int s = 32; s; s >>= 1){ p0 += __shfl_xor(p0, s, 64); p1 += __shfl_xor(p1, s, 64); }
    if (lane == 0){
        z[(size_t)wid*2]     = p0 + postb[0];
        z[(size_t)wid*2 + 1] = p1 + postb[1];
    }
}

// ---- final edge scores (f32 out) ----
__global__ __launch_bounds__(256) void k_score(const int* __restrict__ eli,
        const float* __restrict__ z, const float* __restrict__ rel,
        float* __restrict__ out)
{
    int tid = blockIdx.x*blockDim.x + threadIdx.x;
    if (tid >= R_REL*L_EDGES) return;
    int r = tid < L_EDGES ? 0 : (tid < 2*L_EDGES ? 1 : 2);
    int l = tid - r*L_EDGES;
    int hn = eli[(size_t)r*2*L_EDGES + l];
    int tn = eli[(size_t)r*2*L_EDGES + L_EDGES + l];
    float hr = z[(size_t)hn*2], hi = z[(size_t)hn*2+1];
    float tr = z[(size_t)tn*2], ti = z[(size_t)tn*2+1];
    float rr = rel[2*r], ri = rel[2*r+1];
    out[tid] = hr*rr*tr + hi*rr*ti + hr*ri*ti - hi*ri*tr;
}

extern "C" void kernel_launch(void* const* d_in, const int* in_sizes, int n_in,
                              void* d_out, int out_size, void* d_ws, size_t ws_size,
                              hipStream_t stream)
{
    const float* x      = (const float*)d_in[0];
    const int*   ei     = (const int*)d_in[1];
    const int*   eli    = (const int*)d_in[2];
    const float* past1  = (const float*)d_in[3];
    const float* past2  = (const float*)d_in[4];
    const float* W1rel  = (const float*)d_in[5];
    const float* b1rel  = (const float*)d_in[6];
    const float* W1root = (const float*)d_in[7];
    const float* g1Wi   = (const float*)d_in[8];
    const float* g1Wh   = (const float*)d_in[9];
    const float* g1bi   = (const float*)d_in[10];
    const float* g1bh   = (const float*)d_in[11];
    const float* k1W    = (const float*)d_in[12];
    const float* k1b    = (const float*)d_in[13];
    const float* q1     = (const float*)d_in[14];
    const float* W2rel  = (const float*)d_in[15];
    const float* b2rel  = (const float*)d_in[16];
    const float* W2root = (const float*)d_in[17];
    const float* g2Wi   = (const float*)d_in[18];
    const float* g2Wh   = (const float*)d_in[19];
    const float* g2bi   = (const float*)d_in[20];
    const float* g2bh   = (const float*)d_in[21];
    const float* k2W    = (const float*)d_in[22];
    const float* k2b    = (const float*)d_in[23];
    const float* q2     = (const float*)d_in[24];
    const float* postW  = (const float*)d_in[25];
    const float* postb  = (const float*)d_in[26];
    const float* rel    = (const float*)d_in[27];

    // ---- workspace layout (45.6 MB) ----
    char* ws = (char*)d_ws;
    float* scoreS = (float*)ws;                                  // 128 B
    float* z      = (float*)(ws + 128);                          // N*2 f32 = 800,000 B
    float* aggsem = (float*)(ws + 800128);                       // N*64 f32 = 25.6 MB
    int*   binCur = (int*)  (ws + 26400128);                     // 3*NBP ints = 9,600 B
    unsigned int* sorted = (unsigned int*)(ws + 26409728);       // 3 * NB*BCAP u32 = 19.2 MB
    const size_t WS_NEED = 26409728 + (size_t)3*NB*BCAP*4;       // 45,628,160 B
    if (ws_size < WS_NEED) return;

    // outputs are FLOAT32: scores | cur1 | cur2
    float* out  = (float*)d_out;
    float* cur1 = out + 600000;
    float* cur2 = cur1 + (size_t)R_REL*N_NODES*64;

    hipMemsetAsync(scoreS, 0, 128, stream);
    k_init<<<(3*NBP + 255)/256, 256, 0, stream>>>(binCur);

    const size_t RS = (size_t)N_NODES*64;   // per-relation slice (elems)
    const size_t SS = (size_t)NB*BCAP;      // per-relation sorted slice (elems)

    // ---- layer 1 (edge sort built once per relation; h staged f32 in cur2 slot r) ----
    for (int r = 0; r < R_REL; ++r){
        const int* ei_r = ei + (size_t)r*2*E_EDGES;
        k_reorder<<<RB, 256, 0, stream>>>(ei_r, binCur + r*NBP, sorted + r*SS);
        k_binfused<<<NB, 256, 0, stream>>>(sorted + r*SS, binCur + r*NBP, x,
                                           W1rel + r*4096, b1rel + r*64,
                                           W1root + r*4096, cur2 + r*RS);
        k_gru<<<GB, 256, 0, stream>>>(cur2 + r*RS, past1 + r*RS,
                                      g1Wi, g1Wh, g1bi, g1bh, cur1 + r*RS);
    }
    k_att<<<R_REL*ABPR, 256, 0, stream>>>(cur1, k1W, k1b, q1, scoreS);
    k_combine1<<<(N_NODES*64/4)/256, 256, 0, stream>>>(scoreS, cur1, aggsem);

    // ---- layer 2 (reuses the per-relation edge sort; h aliases cur2 slot r) ----
    for (int r = 0; r < R_REL; ++r){
        k_binfused<<<NB, 256, 0, stream>>>(sorted + r*SS, binCur + r*NBP, aggsem,
                                           W2rel + r*4096, b2rel + r*64,
                                           W2root + r*4096, cur2 + r*RS);
        k_gru<<<GB, 256, 0, stream>>>(cur2 + r*RS, past2 + r*RS,
                                      g2Wi, g2Wh, g2bi, g2bh, cur2 + r*RS);
    }
    k_att<<<R_REL*ABPR, 256, 0, stream>>>(cur2, k2W, k2b, q2, scoreS + 3);
    k_combine2z<<<(N_NODES*64)/256, 256, 0, stream>>>(scoreS + 3, cur2, postW, postb, z);

    // ---- edge scores ----
    k_score<<<(R_REL*L_EDGES + 255)/256, 256, 0, stream>>>(eli, z, rel, out);
}

// Round 2
// 2377.158 us; speedup vs baseline: 1.2115x; 1.2115x over previous
//
#include <hip/hip_runtime.h>

// Problem constants
#define N_NODES 100000
#define HDIM    64
#define R_REL   3
#define E_EDGES 800000
#define L_EDGES 200000
#define NT      (N_NODES/16)   // 6250 node tiles of 16
#define NT3     (3*NT)         // tiles across 3 relations (buffers are r-contiguous)
#define GB3     2048           // fused gru blocks
#define ABPR    391            // att blocks per relation

// dst-binned scatter parameters
#define TS      128            // dst nodes per bin
#define NB      782            // ceil(N/TS)
#define NB3     (3*NB)         // fused binfused grid
#define BCAP    2048           // slot capacity per bin (mean 1023, ~32 sigma margin)
#define NBP     800            // padded per-relation stride of binCur
#define RCH     4096           // edges per reorder block
#define RB      196            // ceil(E/RCH)
#define RB3     (3*RB)

typedef short s16x8 __attribute__((ext_vector_type(8)));
typedef float f32x4 __attribute__((ext_vector_type(4)));
typedef unsigned short u16;

__device__ __forceinline__ u16 f2bf(float f){
    union { float f; unsigned int i; } v; v.f = f;
    unsigned int u = v.i + 0x7FFFu + ((v.i >> 16) & 1u);   // RNE
    return (u16)(u >> 16);
}
__device__ __forceinline__ s16x8 packbf(float4 a, float4 b){
    s16x8 r;
    r[0]=(short)f2bf(a.x); r[1]=(short)f2bf(a.y); r[2]=(short)f2bf(a.z); r[3]=(short)f2bf(a.w);
    r[4]=(short)f2bf(b.x); r[5]=(short)f2bf(b.y); r[6]=(short)f2bf(b.z); r[7]=(short)f2bf(b.w);
    return r;
}
__device__ __forceinline__ s16x8 ldpack(const float* p){   // 8 consecutive f32 -> bf16x8
    return packbf(*(const float4*)p, *(const float4*)(p + 4));
}
__device__ __forceinline__ f32x4 mfma16(s16x8 a, s16x8 b, f32x4 c){
    return __builtin_amdgcn_mfma_f32_16x16x32_bf16(a, b, c, 0, 0, 0);
}
__device__ __forceinline__ float fsigm(float x){
    x = fmaxf(-30.f, fminf(30.f, x));
    return 1.f/(1.f + __expf(-x));
}
__device__ __forceinline__ float ftanh(float x){
    x = fminf(15.f, fmaxf(-15.f, x));
    float e = __expf(2.f*x);
    return (e-1.f)/(e+1.f);
}

// ---- init per-bin cursors: binCur[r*NBP + b] = b*BCAP (positions relative to sorted_r) ----
__global__ __launch_bounds__(256) void k_init(int* __restrict__ binCur)
{
    int i = blockIdx.x*256 + threadIdx.x;
    if (i < 3*NBP) binCur[i] = (i % NBP) * BCAP;
}

// ---- counting-sort edges into dst-bins, all 3 relations fused ----
__global__ __launch_bounds__(256) void k_reorder3(const int* __restrict__ ei,
        int* __restrict__ binCur, unsigned int* __restrict__ sortedAll)
{
    __shared__ int h[NB];
    int r   = blockIdx.x / RB;
    int blk = blockIdx.x % RB;
    const int* ei_r = ei + (size_t)r*2*E_EDGES;
    const int* dst  = ei_r + E_EDGES;
    int* bc = binCur + r*NBP;
    unsigned int* sorted = sortedAll + (size_t)r*NB*BCAP;

    int tid = threadIdx.x;
    int e0 = blk * RCH;
    int e1 = (e0 + RCH < E_EDGES) ? e0 + RCH : E_EDGES;

    for (int i = tid; i < NB; i += 256) h[i] = 0;
    __syncthreads();
    for (int e = e0 + tid; e < e1; e += 256)
        atomicAdd(&h[dst[e] >> 7], 1);
    __syncthreads();
    for (int i = tid; i < NB; i += 256){
        int c = h[i];
        if (c) h[i] = atomicAdd(&bc[i], c);
    }
    __syncthreads();
    for (int e = e0 + tid; e < e1; e += 256){
        int d = dst[e];
        int bin = d >> 7;
        int pos = atomicAdd(&h[bin], 1);
        sorted[pos] = (unsigned)ei_r[e] | ((unsigned)(d & 127) << 17);
    }
}

// ---- binned scatter (LDS accumulate) fused with dense, all 3 relations fused:
//      h[r] = relu(segsum_r(xin[src]) @ Wr[r].T + br[r] + xin @ Wo[r].T) ----
__global__ __launch_bounds__(256) void k_binfused3(
        const unsigned int* __restrict__ sortedAll, const int* __restrict__ binCur,
        const float* __restrict__ xin,
        const float* __restrict__ WrAll, const float* __restrict__ brAll,
        const float* __restrict__ WoAll, float* __restrict__ hbufAll)
{
    __shared__ float tile[TS*64];          // 32 KB
    int r = blockIdx.x / NB;
    int b = blockIdx.x % NB;
    const unsigned int* sorted = sortedAll + (size_t)r*NB*BCAP;
    const float* Wr = WrAll + (size_t)r*4096;
    const float* Wo = WoAll + (size_t)r*4096;
    const float* br = brAll + (size_t)r*64;
    float* hbuf = hbufAll + (size_t)r*N_NODES*64;

    int tid = threadIdx.x;
    int w = tid >> 6, lane = tid & 63;

    {   // zero the tile (8 float4 per thread)
        float4 z4 = {0.f,0.f,0.f,0.f};
        float4* t4 = (float4*)tile;
        #pragma unroll
        for (int i = 0; i < (TS*64/4)/256; ++i) t4[tid + i*256] = z4;
    }
    __syncthreads();

    // scatter phase: each wave takes chunks of 16 edges; 16 gathers in flight
    int i0 = b*BCAP;
    int i1 = binCur[r*NBP + b];
    for (int i = i0 + w*16; i < i1; i += 64){
        if (i + 16 <= i1){
            unsigned pk[16]; float v[16];
            #pragma unroll
            for (int u = 0; u < 16; ++u) pk[u] = sorted[i+u];
            #pragma unroll
            for (int u = 0; u < 16; ++u) v[u] = xin[(size_t)(pk[u] & 0x1FFFFu)*64 + lane];
            #pragma unroll
            for (int u = 0; u < 16; ++u) atomicAdd(&tile[(pk[u] >> 17)*64 + lane], v[u]);
        } else {
            for (int e = i; e < i1; ++e){
                unsigned pk = sorted[e];
                float v = xin[(size_t)(pk & 0x1FFFFu)*64 + lane];
                atomicAdd(&tile[(pk >> 17)*64 + lane], v);
            }
        }
    }
    __syncthreads();

    // dense phase (same MFMA layout as the proven k_dense, A from LDS tile)
    int col = lane & 15, quad = lane >> 4, k0 = quad*8;
    s16x8 fr[4][2], fo[4][2];
    float bias[4];
    #pragma unroll
    for (int c = 0; c < 4; ++c){
        int m = c*16 + col;
        fr[c][0] = ldpack(Wr + m*64 + k0);
        fr[c][1] = ldpack(Wr + m*64 + 32 + k0);
        fo[c][0] = ldpack(Wo + m*64 + k0);
        fo[c][1] = ldpack(Wo + m*64 + 32 + k0);
        bias[c]  = br[m];
    }
    #pragma unroll
    for (int st = 0; st < 2; ++st){
        int s = st*4 + w;                       // subtile 0..7 (16 nodes each)
        int nodeBase = b*TS + s*16;
        if (nodeBase < N_NODES){
            const float* arow = tile + (s*16 + col)*64;
            s16x8 a1h0 = ldpack(arow + k0);
            s16x8 a1h1 = ldpack(arow + 32 + k0);
            int node = nodeBase + col;
            s16x8 a2h0 = ldpack(xin + (size_t)node*64 + k0);
            s16x8 a2h1 = ldpack(xin + (size_t)node*64 + 32 + k0);
            #pragma unroll
            for (int c = 0; c < 4; ++c){
                f32x4 acc = {0.f,0.f,0.f,0.f};
                acc = mfma16(a1h0, fr[c][0], acc);
                acc = mfma16(a1h1, fr[c][1], acc);
                acc = mfma16(a2h0, fo[c][0], acc);
                acc = mfma16(a2h1, fo[c][1], acc);
                #pragma unroll
                for (int ii = 0; ii < 4; ++ii){
                    int row = nodeBase + quad*4 + ii;
                    float vv = acc[ii] + bias[c];
                    hbuf[(size_t)row*64 + c*16 + col] = vv > 0.f ? vv : 0.f;
                }
            }
        }
    }
}

// ---- GRU, all 3 relations fused (weights shared across r; buffers r-contiguous).
//      hbuf MAY ALIAS cur: per-tile barrier after loads. ----
__global__ __launch_bounds__(256) void k_gru3(const float* hbuf, const float* past,
        const float* __restrict__ Wi, const float* __restrict__ Wh,
        const float* __restrict__ bi_, const float* __restrict__ bh_, float* cur)
{
    int w = threadIdx.x >> 6, lane = threadIdx.x & 63;
    int col = lane & 15, quad = lane >> 4, k0 = quad*8;

    s16x8 fwi[3][2], fwh[3][2];
    float vbi[3], vbh[3];
    #pragma unroll
    for (int g = 0; g < 3; ++g){
        int m = g*64 + w*16 + col;
        fwi[g][0] = ldpack(Wi + m*64 + k0);
        fwi[g][1] = ldpack(Wi + m*64 + 32 + k0);
        fwh[g][0] = ldpack(Wh + m*64 + k0);
        fwh[g][1] = ldpack(Wh + m*64 + 32 + k0);
        vbi[g] = bi_[m]; vbh[g] = bh_[m];
    }
    int j = w*16 + col;
    for (int t = blockIdx.x; t < NT3; t += GB3){
        int node = t*16 + col;
        const float* hrow = hbuf + (size_t)node*64;
        const float* prow = past + (size_t)node*64;
        s16x8 ah0 = ldpack(hrow + k0);
        s16x8 ah1 = ldpack(hrow + 32 + k0);
        s16x8 ap0 = ldpack(prow + k0);
        s16x8 ap1 = ldpack(prow + 32 + k0);
        float pv[4];
        #pragma unroll
        for (int i = 0; i < 4; ++i)
            pv[i] = past[(size_t)(t*16 + quad*4 + i)*64 + j];
        // all waves must finish reading h[t] before any wave overwrites cur[t]
        __syncthreads();
        f32x4 gi[3], gh[3];
        #pragma unroll
        for (int g = 0; g < 3; ++g){
            f32x4 z0 = {0.f,0.f,0.f,0.f};
            gi[g] = mfma16(ah1, fwi[g][1], mfma16(ah0, fwi[g][0], z0));
            gh[g] = mfma16(ap1, fwh[g][1], mfma16(ap0, fwh[g][0], z0));
        }
        #pragma unroll
        for (int i = 0; i < 4; ++i){
            int row = t*16 + quad*4 + i;
            float ir = gi[0][i]+vbi[0], iz = gi[1][i]+vbi[1], in_ = gi[2][i]+vbi[2];
            float hr = gh[0][i]+vbh[0], hz = gh[1][i]+vbh[1], hn = gh[2][i]+vbh[2];
            float rg = fsigm(ir + hr);
            float zg = fsigm(iz + hz);
            float ng = ftanh(in_ + rg*hn);
            cur[(size_t)row*64 + j] = (1.f - zg)*ng + zg*pv[i];
        }
    }
}

// ---- attention score (all rels) ----
__global__ __launch_bounds__(256) void k_att(const float* __restrict__ cur,
        const float* __restrict__ kW, const float* __restrict__ kb,
        const float* __restrict__ q, float* __restrict__ scoreOut)
{
    int r  = blockIdx.x / ABPR;
    int bi = blockIdx.x % ABPR;
    int w = threadIdx.x >> 6, lane = threadIdx.x & 63;
    int col = lane & 15, quad = lane >> 4, k0 = quad*8;

    s16x8 fk[4][2];
    float vkb[4], vq[4];
    #pragma unroll
    for (int c = 0; c < 4; ++c){
        int m = c*16 + col;
        fk[c][0] = ldpack(kW + m*64 + k0);
        fk[c][1] = ldpack(kW + m*64 + 32 + k0);
        vkb[c] = kb[m]; vq[c] = q[m];
    }
    float p = 0.f;
    int wid = bi*4 + w;
    for (int t = wid; t < NT; t += ABPR*4){
        int node = t*16 + col;
        const float* crow = cur + ((size_t)r*N_NODES + node)*64;
        s16x8 a0 = ldpack(crow + k0);
        s16x8 a1 = ldpack(crow + 32 + k0);
        #pragma unroll
        for (int c = 0; c < 4; ++c){
            f32x4 acc = {0.f,0.f,0.f,0.f};
            acc = mfma16(a1, fk[c][1], mfma16(a0, fk[c][0], acc));
            #pragma unroll
            for (int i = 0; i < 4; ++i)
                p += ftanh(acc[i] + vkb[c]) * vq[c];
        }
    }
    #pragma unroll
    for (int o = 32; o; o >>= 1) p += __shfl_xor(p, o, 64);
    if (lane == 0) unsafeAtomicAdd(scoreOut + r, p);
}

// ---- combine1: aggsem(f32) = sum_r softmax(score)[r] * cur[r] ----
__global__ __launch_bounds__(256) void k_combine1(const float* __restrict__ scoreS,
        const float* __restrict__ cur, float* __restrict__ aggsem)
{
    float s0 = scoreS[0]*(1.f/N_NODES), s1 = scoreS[1]*(1.f/N_NODES), s2 = scoreS[2]*(1.f/N_NODES);
    float mx = fmaxf(s0, fmaxf(s1, s2));
    float e0 = __expf(s0-mx), e1 = __expf(s1-mx), e2 = __expf(s2-mx);
    float inv = 1.f/(e0+e1+e2);
    float a0 = e0*inv, a1 = e1*inv, a2 = e2*inv;

    size_t idx = (size_t)blockIdx.x*blockDim.x + threadIdx.x;   // one thread = 4 elems
    const size_t S = (size_t)N_NODES*64;
    float4 v0 = *(const float4*)(cur + idx*4);
    float4 v1 = *(const float4*)(cur + S + idx*4);
    float4 v2 = *(const float4*)(cur + 2*S + idx*4);
    float4 o;
    o.x = a0*v0.x + a1*v1.x + a2*v2.x;
    o.y = a0*v0.y + a1*v1.y + a2*v2.y;
    o.z = a0*v0.z + a1*v1.z + a2*v2.z;
    o.w = a0*v0.w + a1*v1.w + a2*v2.w;
    *(float4*)(aggsem + idx*4) = o;
}

// ---- combine2 + z ----
__global__ __launch_bounds__(256) void k_combine2z(const float* __restrict__ scoreS,
        const float* __restrict__ cur2, const float* __restrict__ postW,
        const float* __restrict__ postb, float* __restrict__ z)
{
    float s0 = scoreS[0]*(1.f/N_NODES), s1 = scoreS[1]*(1.f/N_NODES), s2 = scoreS[2]*(1.f/N_NODES);
    float mx = fmaxf(s0, fmaxf(s1, s2));
    float e0 = __expf(s0-mx), e1 = __expf(s1-mx), e2 = __expf(s2-mx);
    float inv = 1.f/(e0+e1+e2);
    float a0 = e0*inv, a1 = e1*inv, a2 = e2*inv;

    int wid = (int)((blockIdx.x*blockDim.x + threadIdx.x) >> 6);  // node
    int lane = threadIdx.x & 63;
    const size_t S = (size_t)N_NODES*64;
    size_t o = (size_t)wid*64 + lane;
    float v = a0*cur2[o] + a1*cur2[S + o] + a2*cur2[2*S + o];
    float p0 = v * postW[lane];
    float p1 = v * postW[64 + lane];
    #pragma unroll
    for (int s = 32; s; s >>= 1){ p0 += __shfl_xor(p0, s, 64); p1 += __shfl_xor(p1, s, 64); }
    if (lane == 0){
        z[(size_t)wid*2]     = p0 + postb[0];
        z[(size_t)wid*2 + 1] = p1 + postb[1];
    }
}

// ---- final edge scores (f32 out) ----
__global__ __launch_bounds__(256) void k_score(const int* __restrict__ eli,
        const float* __restrict__ z, const float* __restrict__ rel,
        float* __restrict__ out)
{
    int tid = blockIdx.x*blockDim.x + threadIdx.x;
    if (tid >= R_REL*L_EDGES) return;
    int r = tid < L_EDGES ? 0 : (tid < 2*L_EDGES ? 1 : 2);
    int l = tid - r*L_EDGES;
    int hn = eli[(size_t)r*2*L_EDGES + l];
    int tn = eli[(size_t)r*2*L_EDGES + L_EDGES + l];
    float hr = z[(size_t)hn*2], hi = z[(size_t)hn*2+1];
    float tr = z[(size_t)tn*2], ti = z[(size_t)tn*2+1];
    float rr = rel[2*r], ri = rel[2*r+1];
    out[tid] = hr*rr*tr + hi*rr*ti + hr*ri*ti - hi*ri*tr;
}

extern "C" void kernel_launch(void* const* d_in, const int* in_sizes, int n_in,
                              void* d_out, int out_size, void* d_ws, size_t ws_size,
                              hipStream_t stream)
{
    const float* x      = (const float*)d_in[0];
    const int*   ei     = (const int*)d_in[1];
    const int*   eli    = (const int*)d_in[2];
    const float* past1  = (const float*)d_in[3];
    const float* past2  = (const float*)d_in[4];
    const float* W1rel  = (const float*)d_in[5];
    const float* b1rel  = (const float*)d_in[6];
    const float* W1root = (const float*)d_in[7];
    const float* g1Wi   = (const float*)d_in[8];
    const float* g1Wh   = (const float*)d_in[9];
    const float* g1bi   = (const float*)d_in[10];
    const float* g1bh   = (const float*)d_in[11];
    const float* k1W    = (const float*)d_in[12];
    const float* k1b    = (const float*)d_in[13];
    const float* q1     = (const float*)d_in[14];
    const float* W2rel  = (const float*)d_in[15];
    const float* b2rel  = (const float*)d_in[16];
    const float* W2root = (const float*)d_in[17];
    const float* g2Wi   = (const float*)d_in[18];
    const float* g2Wh   = (const float*)d_in[19];
    const float* g2bi   = (const float*)d_in[20];
    const float* g2bh   = (const float*)d_in[21];
    const float* k2W    = (const float*)d_in[22];
    const float* k2b    = (const float*)d_in[23];
    const float* q2     = (const float*)d_in[24];
    const float* postW  = (const float*)d_in[25];
    const float* postb  = (const float*)d_in[26];
    const float* rel    = (const float*)d_in[27];

    // ---- workspace layout (45.6 MB) ----
    char* ws = (char*)d_ws;
    float* scoreS = (float*)ws;                                  // 128 B
    float* z      = (float*)(ws + 128);                          // N*2 f32 = 800,000 B
    float* aggsem = (float*)(ws + 800128);                       // N*64 f32 = 25.6 MB
    int*   binCur = (int*)  (ws + 26400128);                     // 3*NBP ints = 9,600 B
    unsigned int* sorted = (unsigned int*)(ws + 26409728);       // 3 * NB*BCAP u32 = 19.2 MB
    const size_t WS_NEED = 26409728 + (size_t)3*NB*BCAP*4;       // 45,628,160 B
    if (ws_size < WS_NEED) return;

    // outputs are FLOAT32: scores | cur1 | cur2
    float* out  = (float*)d_out;
    float* cur1 = out + 600000;
    float* cur2 = cur1 + (size_t)R_REL*N_NODES*64;

    hipMemsetAsync(scoreS, 0, 128, stream);
    k_init<<<(3*NBP + 255)/256, 256, 0, stream>>>(binCur);

    // edge sort built once, reused by both layers
    k_reorder3<<<RB3, 256, 0, stream>>>(ei, binCur, sorted);

    // ---- layer 1 (h staged f32 in cur2; real cur2 written later) ----
    k_binfused3<<<NB3, 256, 0, stream>>>(sorted, binCur, x, W1rel, b1rel, W1root, cur2);
    k_gru3<<<GB3, 256, 0, stream>>>(cur2, past1, g1Wi, g1Wh, g1bi, g1bh, cur1);
    k_att<<<R_REL*ABPR, 256, 0, stream>>>(cur1, k1W, k1b, q1, scoreS);
    k_combine1<<<(N_NODES*64/4)/256, 256, 0, stream>>>(scoreS, cur1, aggsem);

    // ---- layer 2 (h aliases cur2; k_gru3's per-tile barrier makes that safe) ----
    k_binfused3<<<NB3, 256, 0, stream>>>(sorted, binCur, aggsem, W2rel, b2rel, W2root, cur2);
    k_gru3<<<GB3, 256, 0, stream>>>(cur2, past2, g2Wi, g2Wh, g2bi, g2bh, cur2);
    k_att<<<R_REL*ABPR, 256, 0, stream>>>(cur2, k2W, k2b, q2, scoreS + 3);
    k_combine2z<<<(N_NODES*64)/256, 256, 0, stream>>>(scoreS + 3, cur2, postW, postb, z);

    // ---- edge scores ----
    k_score<<<(R_REL*L_EDGES + 255)/256, 256, 0, stream>>>(eli, z, rel, out);
}

// Round 3
// 2314.370 us; speedup vs baseline: 1.2444x; 1.0271x over previous
//
#include <hip/hip_runtime.h>

// Problem constants
#define N_NODES 100000
#define HDIM    64
#define R_REL   3
#define E_EDGES 800000
#define L_EDGES 200000
#define NT      (N_NODES/16)   // 6250 node tiles of 16
#define NT3     (3*NT)         // tiles across 3 relations (buffers are r-contiguous)
#define GB3     2048           // fused gru blocks
#define ABPR    391            // att blocks per relation

// dst-binned scatter parameters
#define TS      64             // dst nodes per bin
#define NB      1563           // ceil(N/TS)
#define NB3     (3*NB)         // fused binfused grid
#define BCAP    1024           // slot capacity per bin (mean 512, sigma ~23 -> huge margin)
#define NBP     1568           // padded per-relation stride of binCur
#define RCH     4096           // edges per reorder block
#define RB      196            // ceil(E/RCH)
#define RB3     (3*RB)
#define INVALID_PK (1u<<24)    // pad marker: src bits = 0 (safe load), flag bit 24

typedef short s16x8 __attribute__((ext_vector_type(8)));
typedef float f32x4 __attribute__((ext_vector_type(4)));
typedef unsigned short u16;

__device__ __forceinline__ u16 f2bf(float f){
    union { float f; unsigned int i; } v; v.f = f;
    unsigned int u = v.i + 0x7FFFu + ((v.i >> 16) & 1u);   // RNE
    return (u16)(u >> 16);
}
__device__ __forceinline__ s16x8 packbf(float4 a, float4 b){
    s16x8 r;
    r[0]=(short)f2bf(a.x); r[1]=(short)f2bf(a.y); r[2]=(short)f2bf(a.z); r[3]=(short)f2bf(a.w);
    r[4]=(short)f2bf(b.x); r[5]=(short)f2bf(b.y); r[6]=(short)f2bf(b.z); r[7]=(short)f2bf(b.w);
    return r;
}
__device__ __forceinline__ s16x8 ldpack(const float* p){   // 8 consecutive f32 -> bf16x8
    return packbf(*(const float4*)p, *(const float4*)(p + 4));
}
__device__ __forceinline__ f32x4 mfma16(s16x8 a, s16x8 b, f32x4 c){
    return __builtin_amdgcn_mfma_f32_16x16x32_bf16(a, b, c, 0, 0, 0);
}
__device__ __forceinline__ float fsigm(float x){
    x = fmaxf(-30.f, fminf(30.f, x));
    return 1.f/(1.f + __expf(-x));
}
__device__ __forceinline__ float ftanh(float x){
    x = fminf(15.f, fmaxf(-15.f, x));
    float e = __expf(2.f*x);
    return (e-1.f)/(e+1.f);
}

// ---- f32 -> bf16 row conversion (x) ----
__global__ __launch_bounds__(256) void k_tobf(const float* __restrict__ in,
        u16* __restrict__ out, int n8)
{
    int idx = blockIdx.x*256 + threadIdx.x;
    if (idx < n8){
        s16x8 v = ldpack(in + (size_t)idx*8);
        *(s16x8*)(out + (size_t)idx*8) = v;
    }
}

// ---- init per-bin cursors: binCur[r*NBP + b] = b*BCAP ----
__global__ __launch_bounds__(256) void k_init(int* __restrict__ binCur)
{
    int i = blockIdx.x*256 + threadIdx.x;
    if (i < 3*NBP) binCur[i] = (i % NBP) * BCAP;
}

// ---- counting-sort edges into dst-bins, all 3 relations fused ----
__global__ __launch_bounds__(256) void k_reorder3(const int* __restrict__ ei,
        int* __restrict__ binCur, unsigned int* __restrict__ sortedAll)
{
    __shared__ int h[NB];
    int r   = blockIdx.x / RB;
    int blk = blockIdx.x % RB;
    const int* ei_r = ei + (size_t)r*2*E_EDGES;
    const int* dst  = ei_r + E_EDGES;
    int* bc = binCur + r*NBP;
    unsigned int* sorted = sortedAll + (size_t)r*NB*BCAP;

    int tid = threadIdx.x;
    int e0 = blk * RCH;
    int e1 = (e0 + RCH < E_EDGES) ? e0 + RCH : E_EDGES;

    for (int i = tid; i < NB; i += 256) h[i] = 0;
    __syncthreads();
    for (int e = e0 + tid; e < e1; e += 256)
        atomicAdd(&h[dst[e] >> 6], 1);
    __syncthreads();
    for (int i = tid; i < NB; i += 256){
        int c = h[i];
        if (c) h[i] = atomicAdd(&bc[i], c);
    }
    __syncthreads();
    for (int e = e0 + tid; e < e1; e += 256){
        int d = dst[e];
        int bin = d >> 6;
        int pos = atomicAdd(&h[bin], 1);
        sorted[pos] = (unsigned)ei_r[e] | ((unsigned)(d & 63) << 17);
    }
}

// ---- pad each bin's slot range to a multiple of 16 with INVALID_PK markers ----
__global__ __launch_bounds__(256) void k_pad(const int* __restrict__ binCur,
        unsigned int* __restrict__ sortedAll)
{
    int g = blockIdx.x*16 + (threadIdx.x >> 4);   // bin id over 3*NB
    if (g >= 3*NB) return;
    int r = g / NB, b = g % NB;
    int cnt = binCur[r*NBP + b] - b*BCAP;
    int end = (cnt + 15) & ~15;
    int s = cnt + (threadIdx.x & 15);
    if (s < end)
        sortedAll[(size_t)r*NB*BCAP + (size_t)b*BCAP + s] = INVALID_PK;
}

// ---- binned scatter (bf16 gather, f32 LDS accumulate, sw-pipelined) fused with dense:
//      h[r] = relu(segsum_r(xbf[src]) @ Wr[r].T + br[r] + xbf @ Wo[r].T) ----
__global__ __launch_bounds__(256) void k_binfused3(
        const unsigned int* __restrict__ sortedAll, const int* __restrict__ binCur,
        const u16* __restrict__ xbf,
        const float* __restrict__ WrAll, const float* __restrict__ brAll,
        const float* __restrict__ WoAll, float* __restrict__ hbufAll)
{
    __shared__ float tile[TS*64];          // 16 KB
    int r = blockIdx.x / NB;
    int b = blockIdx.x % NB;
    const unsigned int* sorted = sortedAll + (size_t)r*NB*BCAP;
    const float* Wr = WrAll + (size_t)r*4096;
    const float* Wo = WoAll + (size_t)r*4096;
    const float* br = brAll + (size_t)r*64;
    float* hbuf = hbufAll + (size_t)r*N_NODES*64;

    int tid = threadIdx.x;
    int w = tid >> 6, lane = tid & 63;

    {   // zero the tile (4 float4 per thread)
        float4 z4 = {0.f,0.f,0.f,0.f};
        float4* t4 = (float4*)tile;
        #pragma unroll
        for (int i = 0; i < (TS*64/4)/256; ++i) t4[tid + i*256] = z4;
    }
    __syncthreads();

    // ---- scatter phase: 16 edges/chunk/wave, lane-paired bf16 gather (2 edges/load),
    //      depth-2 software pipeline (pk and v waits land one iteration late) ----
    {
        int halfw = lane >> 5;             // 0: even edge of pair, 1: odd edge
        int fo2   = (lane & 31)*2;         // feature index (u16 units)
        int i0 = b*BCAP;
        int cnt = binCur[r*NBP + b] - i0;
        int iEnd = i0 + ((cnt + 15) & ~15);   // padded with INVALID_PK by k_pad

        uint4 qA0,qA1,qA2,qA3, qB0,qB1,qB2,qB3;
        unsigned pkA[8], vA[8], pkB[8], vB[8];

#define LDQ(q0,q1,q2,q3, base) do{ \
        const uint4* _sp = (const uint4*)(sorted + (base)); \
        q0=_sp[0]; q1=_sp[1]; q2=_sp[2]; q3=_sp[3]; }while(0)

#define DEC1(lo_,hi_, pk, v, p) do{ \
        unsigned s_ = halfw ? (hi_) : (lo_); \
        pk[p] = s_; \
        v[p]  = *(const unsigned*)(xbf + (size_t)(s_ & 0x1FFFFu)*64 + fo2); }while(0)

#define DECV(q0,q1,q2,q3, pk, v) do{ \
        DEC1(q0.x,q0.y,pk,v,0); DEC1(q0.z,q0.w,pk,v,1); \
        DEC1(q1.x,q1.y,pk,v,2); DEC1(q1.z,q1.w,pk,v,3); \
        DEC1(q2.x,q2.y,pk,v,4); DEC1(q2.z,q2.w,pk,v,5); \
        DEC1(q3.x,q3.y,pk,v,6); DEC1(q3.z,q3.w,pk,v,7); }while(0)

#define ATOM(pk, v) do{ \
        _Pragma("unroll") \
        for (int p = 0; p < 8; ++p){ \
            unsigned k_ = pk[p]; \
            if (k_ < INVALID_PK){ \
                unsigned w_ = v[p]; \
                union{unsigned u; float f;} l_, h_; \
                l_.u = w_ << 16; h_.u = w_ & 0xFFFF0000u; \
                int d_ = (k_ >> 17) & 63; \
                float* tp = tile + d_*64 + fo2; \
                atomicAdd(tp,     l_.f); \
                atomicAdd(tp + 1, h_.f); \
            } } }while(0)

        int i = i0 + w*16;
        if (i < iEnd){
            LDQ(qA0,qA1,qA2,qA3, i);
            bool moreB = (i + 64) < iEnd;
            if (moreB) LDQ(qB0,qB1,qB2,qB3, i + 64);
            DECV(qA0,qA1,qA2,qA3, pkA, vA);
            i += 128;
            while (moreB){
                bool moreA = (i < iEnd);
                if (moreA) LDQ(qA0,qA1,qA2,qA3, i);
                DECV(qB0,qB1,qB2,qB3, pkB, vB);
                ATOM(pkA, vA);
                i += 64;
                if (!moreA){ ATOM(pkB, vB); goto sdone; }
                moreB = (i < iEnd);
                if (moreB) LDQ(qB0,qB1,qB2,qB3, i);
                DECV(qA0,qA1,qA2,qA3, pkA, vA);
                ATOM(pkB, vB);
                i += 64;
            }
            ATOM(pkA, vA);
            sdone: ;
        }
    }
    __syncthreads();

    // ---- dense phase: wave w owns subtile w (16 nodes); A from LDS tile (f32->bf16),
    //      root operand direct bf16 load ----
    int col = lane & 15, quad = lane >> 4, k0 = quad*8;
    s16x8 fr[4][2], fo[4][2];
    float bias[4];
    #pragma unroll
    for (int c = 0; c < 4; ++c){
        int m = c*16 + col;
        fr[c][0] = ldpack(Wr + m*64 + k0);
        fr[c][1] = ldpack(Wr + m*64 + 32 + k0);
        fo[c][0] = ldpack(Wo + m*64 + k0);
        fo[c][1] = ldpack(Wo + m*64 + 32 + k0);
        bias[c]  = br[m];
    }
    int nodeBase = b*TS + w*16;
    if (nodeBase < N_NODES){
        const float* arow = tile + (w*16 + col)*64;
        s16x8 a1h0 = ldpack(arow + k0);
        s16x8 a1h1 = ldpack(arow + 32 + k0);
        int node = nodeBase + col;
        s16x8 a2h0 = *(const s16x8*)(xbf + (size_t)node*64 + k0);
        s16x8 a2h1 = *(const s16x8*)(xbf + (size_t)node*64 + 32 + k0);
        #pragma unroll
        for (int c = 0; c < 4; ++c){
            f32x4 acc = {0.f,0.f,0.f,0.f};
            acc = mfma16(a1h0, fr[c][0], acc);
            acc = mfma16(a1h1, fr[c][1], acc);
            acc = mfma16(a2h0, fo[c][0], acc);
            acc = mfma16(a2h1, fo[c][1], acc);
            #pragma unroll
            for (int ii = 0; ii < 4; ++ii){
                int row = nodeBase + quad*4 + ii;
                float vv = acc[ii] + bias[c];
                hbuf[(size_t)row*64 + c*16 + col] = vv > 0.f ? vv : 0.f;
            }
        }
    }
}

// ---- GRU, all 3 relations fused (weights shared across r; buffers r-contiguous).
//      hbuf MAY ALIAS cur: per-tile barrier after loads. ----
__global__ __launch_bounds__(256) void k_gru3(const float* hbuf, const float* past,
        const float* __restrict__ Wi, const float* __restrict__ Wh,
        const float* __restrict__ bi_, const float* __restrict__ bh_, float* cur)
{
    int w = threadIdx.x >> 6, lane = threadIdx.x & 63;
    int col = lane & 15, quad = lane >> 4, k0 = quad*8;

    s16x8 fwi[3][2], fwh[3][2];
    float vbi[3], vbh[3];
    #pragma unroll
    for (int g = 0; g < 3; ++g){
        int m = g*64 + w*16 + col;
        fwi[g][0] = ldpack(Wi + m*64 + k0);
        fwi[g][1] = ldpack(Wi + m*64 + 32 + k0);
        fwh[g][0] = ldpack(Wh + m*64 + k0);
        fwh[g][1] = ldpack(Wh + m*64 + 32 + k0);
        vbi[g] = bi_[m]; vbh[g] = bh_[m];
    }
    int j = w*16 + col;
    for (int t = blockIdx.x; t < NT3; t += GB3){
        int node = t*16 + col;
        const float* hrow = hbuf + (size_t)node*64;
        const float* prow = past + (size_t)node*64;
        s16x8 ah0 = ldpack(hrow + k0);
        s16x8 ah1 = ldpack(hrow + 32 + k0);
        s16x8 ap0 = ldpack(prow + k0);
        s16x8 ap1 = ldpack(prow + 32 + k0);
        float pv[4];
        #pragma unroll
        for (int i = 0; i < 4; ++i)
            pv[i] = past[(size_t)(t*16 + quad*4 + i)*64 + j];
        // all waves must finish reading h[t] before any wave overwrites cur[t]
        __syncthreads();
        f32x4 gi[3], gh[3];
        #pragma unroll
        for (int g = 0; g < 3; ++g){
            f32x4 z0 = {0.f,0.f,0.f,0.f};
            gi[g] = mfma16(ah1, fwi[g][1], mfma16(ah0, fwi[g][0], z0));
            gh[g] = mfma16(ap1, fwh[g][1], mfma16(ap0, fwh[g][0], z0));
        }
        #pragma unroll
        for (int i = 0; i < 4; ++i){
            int row = t*16 + quad*4 + i;
            float ir = gi[0][i]+vbi[0], iz = gi[1][i]+vbi[1], in_ = gi[2][i]+vbi[2];
            float hr = gh[0][i]+vbh[0], hz = gh[1][i]+vbh[1], hn = gh[2][i]+vbh[2];
            float rg = fsigm(ir + hr);
            float zg = fsigm(iz + hz);
            float ng = ftanh(in_ + rg*hn);
            cur[(size_t)row*64 + j] = (1.f - zg)*ng + zg*pv[i];
        }
    }
}

// ---- attention score (all rels) ----
__global__ __launch_bounds__(256) void k_att(const float* __restrict__ cur,
        const float* __restrict__ kW, const float* __restrict__ kb,
        const float* __restrict__ q, float* __restrict__ scoreOut)
{
    int r  = blockIdx.x / ABPR;
    int bi = blockIdx.x % ABPR;
    int w = threadIdx.x >> 6, lane = threadIdx.x & 63;
    int col = lane & 15, quad = lane >> 4, k0 = quad*8;

    s16x8 fk[4][2];
    float vkb[4], vq[4];
    #pragma unroll
    for (int c = 0; c < 4; ++c){
        int m = c*16 + col;
        fk[c][0] = ldpack(kW + m*64 + k0);
        fk[c][1] = ldpack(kW + m*64 + 32 + k0);
        vkb[c] = kb[m]; vq[c] = q[m];
    }
    float p = 0.f;
    int wid = bi*4 + w;
    for (int t = wid; t < NT; t += ABPR*4){
        int node = t*16 + col;
        const float* crow = cur + ((size_t)r*N_NODES + node)*64;
        s16x8 a0 = ldpack(crow + k0);
        s16x8 a1 = ldpack(crow + 32 + k0);
        #pragma unroll
        for (int c = 0; c < 4; ++c){
            f32x4 acc = {0.f,0.f,0.f,0.f};
            acc = mfma16(a1, fk[c][1], mfma16(a0, fk[c][0], acc));
            #pragma unroll
            for (int i = 0; i < 4; ++i)
                p += ftanh(acc[i] + vkb[c]) * vq[c];
        }
    }
    #pragma unroll
    for (int o = 32; o; o >>= 1) p += __shfl_xor(p, o, 64);
    if (lane == 0) unsafeAtomicAdd(scoreOut + r, p);
}

// ---- combine1: aggsem(bf16) = sum_r softmax(score)[r] * cur[r] ----
__global__ __launch_bounds__(256) void k_combine1(const float* __restrict__ scoreS,
        const float* __restrict__ cur, u16* __restrict__ aggsembf)
{
    float s0 = scoreS[0]*(1.f/N_NODES), s1 = scoreS[1]*(1.f/N_NODES), s2 = scoreS[2]*(1.f/N_NODES);
    float mx = fmaxf(s0, fmaxf(s1, s2));
    float e0 = __expf(s0-mx), e1 = __expf(s1-mx), e2 = __expf(s2-mx);
    float inv = 1.f/(e0+e1+e2);
    float a0 = e0*inv, a1 = e1*inv, a2 = e2*inv;

    size_t idx = (size_t)blockIdx.x*blockDim.x + threadIdx.x;   // one thread = 8 elems
    const size_t S = (size_t)N_NODES*64;
    const float* p0 = cur + idx*8;
    float4 x0 = *(const float4*)(p0),        x1 = *(const float4*)(p0+4);
    float4 y0 = *(const float4*)(p0+S),      y1 = *(const float4*)(p0+S+4);
    float4 w0 = *(const float4*)(p0+2*S),    w1 = *(const float4*)(p0+2*S+4);
    float4 oA, oB;
    oA.x = a0*x0.x + a1*y0.x + a2*w0.x;  oA.y = a0*x0.y + a1*y0.y + a2*w0.y;
    oA.z = a0*x0.z + a1*y0.z + a2*w0.z;  oA.w = a0*x0.w + a1*y0.w + a2*w0.w;
    oB.x = a0*x1.x + a1*y1.x + a2*w1.x;  oB.y = a0*x1.y + a1*y1.y + a2*w1.y;
    oB.z = a0*x1.z + a1*y1.z + a2*w1.z;  oB.w = a0*x1.w + a1*y1.w + a2*w1.w;
    *(s16x8*)(aggsembf + idx*8) = packbf(oA, oB);
}

// ---- combine2 + z ----
__global__ __launch_bounds__(256) void k_combine2z(const float* __restrict__ scoreS,
        const float* __restrict__ cur2, const float* __restrict__ postW,
        const float* __restrict__ postb, float* __restrict__ z)
{
    float s0 = scoreS[0]*(1.f/N_NODES), s1 = scoreS[1]*(1.f/N_NODES), s2 = scoreS[2]*(1.f/N_NODES);
    float mx = fmaxf(s0, fmaxf(s1, s2));
    float e0 = __expf(s0-mx), e1 = __expf(s1-mx), e2 = __expf(s2-mx);
    float inv = 1.f/(e0+e1+e2);
    float a0 = e0*inv, a1 = e1*inv, a2 = e2*inv;

    int wid = (int)((blockIdx.x*blockDim.x + threadIdx.x) >> 6);  // node
    int lane = threadIdx.x & 63;
    const size_t S = (size_t)N_NODES*64;
    size_t o = (size_t)wid*64 + lane;
    float v = a0*cur2[o] + a1*cur2[S + o] + a2*cur2[2*S + o];
    float p0 = v * postW[lane];
    float p1 = v * postW[64 + lane];
    #pragma unroll
    for (int s = 32; s; s >>= 1){ p0 += __shfl_xor(p0, s, 64); p1 += __shfl_xor(p1, s, 64); }
    if (lane == 0){
        z[(size_t)wid*2]     = p0 + postb[0];
        z[(size_t)wid*2 + 1] = p1 + postb[1];
    }
}

// ---- final edge scores (f32 out) ----
__global__ __launch_bounds__(256) void k_score(const int* __restrict__ eli,
        const float* __restrict__ z, const float* __restrict__ rel,
        float* __restrict__ out)
{
    int tid = blockIdx.x*blockDim.x + threadIdx.x;
    if (tid >= R_REL*L_EDGES) return;
    int r = tid < L_EDGES ? 0 : (tid < 2*L_EDGES ? 1 : 2);
    int l = tid - r*L_EDGES;
    int hn = eli[(size_t)r*2*L_EDGES + l];
    int tn = eli[(size_t)r*2*L_EDGES + L_EDGES + l];
    float hr = z[(size_t)hn*2], hi = z[(size_t)hn*2+1];
    float tr = z[(size_t)tn*2], ti = z[(size_t)tn*2+1];
    float rr = rel[2*r], ri = rel[2*r+1];
    out[tid] = hr*rr*tr + hi*rr*ti + hr*ri*ti - hi*ri*tr;
}

extern "C" void kernel_launch(void* const* d_in, const int* in_sizes, int n_in,
                              void* d_out, int out_size, void* d_ws, size_t ws_size,
                              hipStream_t stream)
{
    const float* x      = (const float*)d_in[0];
    const int*   ei     = (const int*)d_in[1];
    const int*   eli    = (const int*)d_in[2];
    const float* past1  = (const float*)d_in[3];
    const float* past2  = (const float*)d_in[4];
    const float* W1rel  = (const float*)d_in[5];
    const float* b1rel  = (const float*)d_in[6];
    const float* W1root = (const float*)d_in[7];
    const float* g1Wi   = (const float*)d_in[8];
    const float* g1Wh   = (const float*)d_in[9];
    const float* g1bi   = (const float*)d_in[10];
    const float* g1bh   = (const float*)d_in[11];
    const float* k1W    = (const float*)d_in[12];
    const float* k1b    = (const float*)d_in[13];
    const float* q1     = (const float*)d_in[14];
    const float* W2rel  = (const float*)d_in[15];
    const float* b2rel  = (const float*)d_in[16];
    const float* W2root = (const float*)d_in[17];
    const float* g2Wi   = (const float*)d_in[18];
    const float* g2Wh   = (const float*)d_in[19];
    const float* g2bi   = (const float*)d_in[20];
    const float* g2bh   = (const float*)d_in[21];
    const float* k2W    = (const float*)d_in[22];
    const float* k2b    = (const float*)d_in[23];
    const float* q2     = (const float*)d_in[24];
    const float* postW  = (const float*)d_in[25];
    const float* postb  = (const float*)d_in[26];
    const float* rel    = (const float*)d_in[27];

    // ---- workspace layout (45.7 MB) ----
    char* ws = (char*)d_ws;
    float* scoreS   = (float*)ws;                               // 128 B
    float* z        = (float*)(ws + 128);                       // 800,000 B
    u16*   xbf      = (u16*)  (ws + 800128);                    // N*64 bf16 = 12.8 MB
    u16*   asem     = (u16*)  (ws + 13600128);                  // N*64 bf16 = 12.8 MB
    int*   binCur   = (int*)  (ws + 26400128);                  // 3*NBP ints = 18,816 B
    unsigned int* sorted = (unsigned int*)(ws + 26418944);      // 3*NB*BCAP u32 = 19.2 MB
    const size_t WS_NEED = 26418944 + (size_t)3*NB*BCAP*4;      // 45,625,088 B
    if (ws_size < WS_NEED) return;

    // outputs are FLOAT32: scores | cur1 | cur2
    float* out  = (float*)d_out;
    float* cur1 = out + 600000;
    float* cur2 = cur1 + (size_t)R_REL*N_NODES*64;

    hipMemsetAsync(scoreS, 0, 128, stream);
    k_init<<<(3*NBP + 255)/256, 256, 0, stream>>>(binCur);
    k_tobf<<<(N_NODES*64/8 + 255)/256, 256, 0, stream>>>(x, xbf, N_NODES*64/8);

    // edge sort built once, reused by both layers; pad bins to chunk multiple
    k_reorder3<<<RB3, 256, 0, stream>>>(ei, binCur, sorted);
    k_pad<<<(3*NB + 15)/16, 256, 0, stream>>>(binCur, sorted);

    // ---- layer 1 (h staged f32 in cur2; real cur2 written later) ----
    k_binfused3<<<NB3, 256, 0, stream>>>(sorted, binCur, xbf, W1rel, b1rel, W1root, cur2);
    k_gru3<<<GB3, 256, 0, stream>>>(cur2, past1, g1Wi, g1Wh, g1bi, g1bh, cur1);
    k_att<<<R_REL*ABPR, 256, 0, stream>>>(cur1, k1W, k1b, q1, scoreS);
    k_combine1<<<(N_NODES*64/8)/256, 256, 0, stream>>>(scoreS, cur1, asem);

    // ---- layer 2 (h aliases cur2; k_gru3's per-tile barrier makes that safe) ----
    k_binfused3<<<NB3, 256, 0, stream>>>(sorted, binCur, asem, W2rel, b2rel, W2root, cur2);
    k_gru3<<<GB3, 256, 0, stream>>>(cur2, past2, g2Wi, g2Wh, g2bi, g2bh, cur2);
    k_att<<<R_REL*ABPR, 256, 0, stream>>>(cur2, k2W, k2b, q2, scoreS + 3);
    k_combine2z<<<(N_NODES*64)/256, 256, 0, stream>>>(scoreS + 3, cur2, postW, postb, z);

    // ---- edge scores ----
    k_score<<<(R_REL*L_EDGES + 255)/256, 256, 0, stream>>>(eli, z, rel, out);
}

// Round 4
// 1447.026 us; speedup vs baseline: 1.9903x; 1.5994x over previous
//
#include <hip/hip_runtime.h>

// Problem constants
#define N_NODES 100000
#define HDIM    64
#define R_REL   3
#define E_EDGES 800000
#define L_EDGES 200000
#define NT      (N_NODES/16)   // 6250 node tiles of 16
#define ABPR    391            // att blocks per relation

// grids
#define AGB     25000          // k_agg blocks (4 nodes/block, one relation)
#define DGB     1563           // k_densegru blocks (64 nodes/block, one relation)
#define HGB     9375           // hist/fill blocks (3E/256)
#define BGB     1172           // base blocks (300000/256 rounded up)

#define HSTRIDE 68             // padded LDS row stride (floats) for h transpose tile

typedef short s16x8 __attribute__((ext_vector_type(8)));
typedef float f32x4 __attribute__((ext_vector_type(4)));
typedef unsigned short u16;

__device__ __forceinline__ u16 f2bf(float f){
    union { float f; unsigned int i; } v; v.f = f;
    unsigned int u = v.i + 0x7FFFu + ((v.i >> 16) & 1u);   // RNE
    return (u16)(u >> 16);
}
__device__ __forceinline__ s16x8 packbf(float4 a, float4 b){
    s16x8 r;
    r[0]=(short)f2bf(a.x); r[1]=(short)f2bf(a.y); r[2]=(short)f2bf(a.z); r[3]=(short)f2bf(a.w);
    r[4]=(short)f2bf(b.x); r[5]=(short)f2bf(b.y); r[6]=(short)f2bf(b.z); r[7]=(short)f2bf(b.w);
    return r;
}
__device__ __forceinline__ s16x8 ldpack(const float* p){   // 8 consecutive f32 -> bf16x8
    return packbf(*(const float4*)p, *(const float4*)(p + 4));
}
__device__ __forceinline__ f32x4 mfma16(s16x8 a, s16x8 b, f32x4 c){
    return __builtin_amdgcn_mfma_f32_16x16x32_bf16(a, b, c, 0, 0, 0);
}
__device__ __forceinline__ float fsigm(float x){
    x = fmaxf(-30.f, fminf(30.f, x));
    return 1.f/(1.f + __expf(-x));
}
__device__ __forceinline__ float ftanh(float x){
    x = fminf(15.f, fmaxf(-15.f, x));
    float e = __expf(2.f*x);
    return (e-1.f)/(e+1.f);
}

// ---- f32 -> bf16 row conversion (x) ----
__global__ __launch_bounds__(256) void k_tobf(const float* __restrict__ in,
        u16* __restrict__ out, int n8)
{
    int idx = blockIdx.x*256 + threadIdx.x;
    if (idx < n8){
        s16x8 v = ldpack(in + (size_t)idx*8);
        *(s16x8*)(out + (size_t)idx*8) = v;
    }
}

// ---- CSR prep 1: per-node in-degree histogram, all 3 relations ----
__global__ __launch_bounds__(256) void k_hist3(const int* __restrict__ ei,
        int* __restrict__ deg)
{
    int tid = blockIdx.x*256 + threadIdx.x;            // < 3*E exactly
    int r = tid < E_EDGES ? 0 : (tid < 2*E_EDGES ? 1 : 2);
    int e = tid - r*E_EDGES;
    int dst = ei[(size_t)r*2*E_EDGES + E_EDGES + e];
    atomicAdd(deg + r*N_NODES + dst, 1);
}

// ---- CSR prep 2: exact base offsets via wave scan + one atomic per wave ----
__global__ __launch_bounds__(256) void k_base3(const int* __restrict__ deg,
        int* __restrict__ baseA, int* __restrict__ curA, int* __restrict__ cursor)
{
    int i = blockIdx.x*256 + threadIdx.x;              // over 3*N
    int lane = threadIdx.x & 63;
    int d = (i < 3*N_NODES) ? deg[i] : 0;
    int p = d;                                          // inclusive wave scan
    #pragma unroll
    for (int off = 1; off < 64; off <<= 1){
        int t = __shfl_up(p, off, 64);
        if (lane >= off) p += t;
    }
    int waveTot = __shfl(p, 63, 64);
    int wb = 0;
    if (lane == 63) wb = atomicAdd(cursor, waveTot);
    wb = __shfl(wb, 63, 64);
    int myBase = wb + p - d;                            // exclusive
    if (i < 3*N_NODES){ baseA[i] = myBase; curA[i] = myBase; }
}

// ---- CSR prep 3: scatter src ids into per-node slot lists ----
__global__ __launch_bounds__(256) void k_fill3(const int* __restrict__ ei,
        int* __restrict__ curA, unsigned int* __restrict__ slots)
{
    int tid = blockIdx.x*256 + threadIdx.x;            // < 3*E exactly
    int r = tid < E_EDGES ? 0 : (tid < 2*E_EDGES ? 1 : 2);
    int e = tid - r*E_EDGES;
    int src = ei[(size_t)r*2*E_EDGES + e];
    int dst = ei[(size_t)r*2*E_EDGES + E_EDGES + e];
    int pos = atomicAdd(curA + r*N_NODES + dst, 1);
    slots[pos] = (unsigned)src;
}

// ---- aggregate (one relation): one WAVE per node, no atomics, no LDS.
//      aggbf[n] = bf16( sum_{e in in(n)} xin[src_e] )  (f32 accumulate) ----
__global__ __launch_bounds__(256) void k_agg(const int* __restrict__ degR,
        const int* __restrict__ baseR, const unsigned int* __restrict__ slots,
        const u16* __restrict__ xin, u16* __restrict__ aggbf)
{
    int w = threadIdx.x >> 6, lane = threadIdx.x & 63;
    int node = blockIdx.x*4 + w;                        // grid exact: 25000*4 = N
    int deg = degR[node], base = baseR[node];
    int halfw = lane >> 5;                              // which edge of a pair
    int fp = lane & 31;                                 // feature pair (2fp, 2fp+1)

    float ax = 0.f, ay = 0.f;
    for (int e0 = 0; e0 < deg; e0 += 8){
        unsigned s[4];
        #pragma unroll
        for (int u = 0; u < 4; ++u){
            int ea = e0 + 2*u + halfw;
            int ec = ea < deg ? ea : deg - 1;
            s[u] = slots[base + ec];
        }
        unsigned v[4];
        #pragma unroll
        for (int u = 0; u < 4; ++u)
            v[u] = *(const unsigned*)(xin + (size_t)s[u]*64 + fp*2);
        #pragma unroll
        for (int u = 0; u < 4; ++u){
            bool ok = (e0 + 2*u + halfw) < deg;
            union{unsigned u32; float f;} lo, hi;
            lo.u32 = v[u] << 16; hi.u32 = v[u] & 0xFFFF0000u;
            ax += ok ? lo.f : 0.f;
            ay += ok ? hi.f : 0.f;
        }
    }
    // combine the two half-wave edge subsets
    ax += __shfl_xor(ax, 32, 64);
    ay += __shfl_xor(ay, 32, 64);
    if (halfw == 0){
        unsigned o = (unsigned)f2bf(ax) | ((unsigned)f2bf(ay) << 16);
        *(unsigned*)(aggbf + (size_t)node*64 + fp*2) = o;   // 32 lanes -> 128 B
    }
}

// ---- fused dense + GRU (one relation): h never hits HBM.
//      dense: wave w computes h for its 16-node subtile -> LDS transpose tile
//      gru:   k_gru3 layout (4 waves cooperate per 16-node tile, wave = feat cols) ----
__global__ __launch_bounds__(256) void k_densegru(
        const u16* __restrict__ aggbf, const u16* __restrict__ xin,
        const float* __restrict__ Wr, const float* __restrict__ br,
        const float* __restrict__ Wo,
        const float* __restrict__ Wi, const float* __restrict__ Wh,
        const float* __restrict__ bi_, const float* __restrict__ bh_,
        const float* __restrict__ past, float* __restrict__ cur)
{
    __shared__ float hs[64*HSTRIDE];                    // 17 KB, padded stride
    int w = threadIdx.x >> 6, lane = threadIdx.x & 63;
    int col = lane & 15, quad = lane >> 4, k0 = quad*8;

    // ---- dense phase ----
    {
        s16x8 fr[4][2], fo[4][2];
        float bias[4];
        #pragma unroll
        for (int c = 0; c < 4; ++c){
            int m = c*16 + col;
            fr[c][0] = ldpack(Wr + m*64 + k0);
            fr[c][1] = ldpack(Wr + m*64 + 32 + k0);
            fo[c][0] = ldpack(Wo + m*64 + k0);
            fo[c][1] = ldpack(Wo + m*64 + 32 + k0);
            bias[c]  = br[m];
        }
        int nb = blockIdx.x*64 + w*16;
        int node = nb + col;
        int nc = node < N_NODES ? node : N_NODES - 1;   // clamp (stores guarded later)
        s16x8 a1h0 = *(const s16x8*)(aggbf + (size_t)nc*64 + k0);
        s16x8 a1h1 = *(const s16x8*)(aggbf + (size_t)nc*64 + 32 + k0);
        s16x8 a2h0 = *(const s16x8*)(xin   + (size_t)nc*64 + k0);
        s16x8 a2h1 = *(const s16x8*)(xin   + (size_t)nc*64 + 32 + k0);
        #pragma unroll
        for (int c = 0; c < 4; ++c){
            f32x4 acc = {0.f,0.f,0.f,0.f};
            acc = mfma16(a1h0, fr[c][0], acc);
            acc = mfma16(a1h1, fr[c][1], acc);
            acc = mfma16(a2h0, fo[c][0], acc);
            acc = mfma16(a2h1, fo[c][1], acc);
            #pragma unroll
            for (int ii = 0; ii < 4; ++ii){
                float vv = acc[ii] + bias[c];
                hs[(w*16 + quad*4 + ii)*HSTRIDE + c*16 + col] = vv > 0.f ? vv : 0.f;
            }
        }
    }
    __syncthreads();

    // ---- gru phase ----
    s16x8 fwi[3][2], fwh[3][2];
    float vbi[3], vbh[3];
    #pragma unroll
    for (int g = 0; g < 3; ++g){
        int m = g*64 + w*16 + col;
        fwi[g][0] = ldpack(Wi + m*64 + k0);
        fwi[g][1] = ldpack(Wi + m*64 + 32 + k0);
        fwh[g][0] = ldpack(Wh + m*64 + k0);
        fwh[g][1] = ldpack(Wh + m*64 + 32 + k0);
        vbi[g] = bi_[m]; vbh[g] = bh_[m];
    }
    int j = w*16 + col;
    #pragma unroll
    for (int t = 0; t < 4; ++t){
        int tb = blockIdx.x*64 + t*16;
        s16x8 ah0 = ldpack(hs + (t*16 + col)*HSTRIDE + k0);
        s16x8 ah1 = ldpack(hs + (t*16 + col)*HSTRIDE + 32 + k0);
        int node = tb + col;
        int nc = node < N_NODES ? node : N_NODES - 1;
        s16x8 ap0 = ldpack(past + (size_t)nc*64 + k0);
        s16x8 ap1 = ldpack(past + (size_t)nc*64 + 32 + k0);
        float pv[4];
        #pragma unroll
        for (int i = 0; i < 4; ++i){
            int rr = tb + quad*4 + i;
            int rc = rr < N_NODES ? rr : N_NODES - 1;
            pv[i] = past[(size_t)rc*64 + j];
        }
        f32x4 gi[3], gh[3];
        #pragma unroll
        for (int g = 0; g < 3; ++g){
            f32x4 z0 = {0.f,0.f,0.f,0.f};
            gi[g] = mfma16(ah1, fwi[g][1], mfma16(ah0, fwi[g][0], z0));
            gh[g] = mfma16(ap1, fwh[g][1], mfma16(ap0, fwh[g][0], z0));
        }
        #pragma unroll
        for (int i = 0; i < 4; ++i){
            int row = tb + quad*4 + i;
            if (row < N_NODES){
                float ir = gi[0][i]+vbi[0], iz = gi[1][i]+vbi[1], in_ = gi[2][i]+vbi[2];
                float hr = gh[0][i]+vbh[0], hz = gh[1][i]+vbh[1], hn = gh[2][i]+vbh[2];
                float rg = fsigm(ir + hr);
                float zg = fsigm(iz + hz);
                float ng = ftanh(in_ + rg*hn);
                cur[(size_t)row*64 + j] = (1.f - zg)*ng + zg*pv[i];
            }
        }
    }
}

// ---- attention score (all rels) ----
__global__ __launch_bounds__(256) void k_att(const float* __restrict__ cur,
        const float* __restrict__ kW, const float* __restrict__ kb,
        const float* __restrict__ q, float* __restrict__ scoreOut)
{
    int r  = blockIdx.x / ABPR;
    int bi = blockIdx.x % ABPR;
    int w = threadIdx.x >> 6, lane = threadIdx.x & 63;
    int col = lane & 15, quad = lane >> 4, k0 = quad*8;

    s16x8 fk[4][2];
    float vkb[4], vq[4];
    #pragma unroll
    for (int c = 0; c < 4; ++c){
        int m = c*16 + col;
        fk[c][0] = ldpack(kW + m*64 + k0);
        fk[c][1] = ldpack(kW + m*64 + 32 + k0);
        vkb[c] = kb[m]; vq[c] = q[m];
    }
    float p = 0.f;
    int wid = bi*4 + w;
    for (int t = wid; t < NT; t += ABPR*4){
        int node = t*16 + col;
        const float* crow = cur + ((size_t)r*N_NODES + node)*64;
        s16x8 a0 = ldpack(crow + k0);
        s16x8 a1 = ldpack(crow + 32 + k0);
        #pragma unroll
        for (int c = 0; c < 4; ++c){
            f32x4 acc = {0.f,0.f,0.f,0.f};
            acc = mfma16(a1, fk[c][1], mfma16(a0, fk[c][0], acc));
            #pragma unroll
            for (int i = 0; i < 4; ++i)
                p += ftanh(acc[i] + vkb[c]) * vq[c];
        }
    }
    #pragma unroll
    for (int o = 32; o; o >>= 1) p += __shfl_xor(p, o, 64);
    if (lane == 0) unsafeAtomicAdd(scoreOut + r, p);
}

// ---- combine1: asem(bf16) = sum_r softmax(score)[r] * cur[r] ----
__global__ __launch_bounds__(256) void k_combine1(const float* __restrict__ scoreS,
        const float* __restrict__ cur, u16* __restrict__ aggsembf)
{
    float s0 = scoreS[0]*(1.f/N_NODES), s1 = scoreS[1]*(1.f/N_NODES), s2 = scoreS[2]*(1.f/N_NODES);
    float mx = fmaxf(s0, fmaxf(s1, s2));
    float e0 = __expf(s0-mx), e1 = __expf(s1-mx), e2 = __expf(s2-mx);
    float inv = 1.f/(e0+e1+e2);
    float a0 = e0*inv, a1 = e1*inv, a2 = e2*inv;

    size_t idx = (size_t)blockIdx.x*blockDim.x + threadIdx.x;   // one thread = 8 elems
    const size_t S = (size_t)N_NODES*64;
    const float* p0 = cur + idx*8;
    float4 x0 = *(const float4*)(p0),        x1 = *(const float4*)(p0+4);
    float4 y0 = *(const float4*)(p0+S),      y1 = *(const float4*)(p0+S+4);
    float4 w0 = *(const float4*)(p0+2*S),    w1 = *(const float4*)(p0+2*S+4);
    float4 oA, oB;
    oA.x = a0*x0.x + a1*y0.x + a2*w0.x;  oA.y = a0*x0.y + a1*y0.y + a2*w0.y;
    oA.z = a0*x0.z + a1*y0.z + a2*w0.z;  oA.w = a0*x0.w + a1*y0.w + a2*w0.w;
    oB.x = a0*x1.x + a1*y1.x + a2*w1.x;  oB.y = a0*x1.y + a1*y1.y + a2*w1.y;
    oB.z = a0*x1.z + a1*y1.z + a2*w1.z;  oB.w = a0*x1.w + a1*y1.w + a2*w1.w;
    *(s16x8*)(aggsembf + idx*8) = packbf(oA, oB);
}

// ---- combine2 + z ----
__global__ __launch_bounds__(256) void k_combine2z(const float* __restrict__ scoreS,
        const float* __restrict__ cur2, const float* __restrict__ postW,
        const float* __restrict__ postb, float* __restrict__ z)
{
    float s0 = scoreS[0]*(1.f/N_NODES), s1 = scoreS[1]*(1.f/N_NODES), s2 = scoreS[2]*(1.f/N_NODES);
    float mx = fmaxf(s0, fmaxf(s1, s2));
    float e0 = __expf(s0-mx), e1 = __expf(s1-mx), e2 = __expf(s2-mx);
    float inv = 1.f/(e0+e1+e2);
    float a0 = e0*inv, a1 = e1*inv, a2 = e2*inv;

    int wid = (int)((blockIdx.x*blockDim.x + threadIdx.x) >> 6);  // node
    int lane = threadIdx.x & 63;
    const size_t S = (size_t)N_NODES*64;
    size_t o = (size_t)wid*64 + lane;
    float v = a0*cur2[o] + a1*cur2[S + o] + a2*cur2[2*S + o];
    float p0 = v * postW[lane];
    float p1 = v * postW[64 + lane];
    #pragma unroll
    for (int s = 32; s; s >>= 1){ p0 += __shfl_xor(p0, s, 64); p1 += __shfl_xor(p1, s, 64); }
    if (lane == 0){
        z[(size_t)wid*2]     = p0 + postb[0];
        z[(size_t)wid*2 + 1] = p1 + postb[1];
    }
}

// ---- final edge scores (f32 out) ----
__global__ __launch_bounds__(256) void k_score(const int* __restrict__ eli,
        const float* __restrict__ z, const float* __restrict__ rel,
        float* __restrict__ out)
{
    int tid = blockIdx.x*blockDim.x + threadIdx.x;
    if (tid >= R_REL*L_EDGES) return;
    int r = tid < L_EDGES ? 0 : (tid < 2*L_EDGES ? 1 : 2);
    int l = tid - r*L_EDGES;
    int hn = eli[(size_t)r*2*L_EDGES + l];
    int tn = eli[(size_t)r*2*L_EDGES + L_EDGES + l];
    float hr = z[(size_t)hn*2], hi = z[(size_t)hn*2+1];
    float tr = z[(size_t)tn*2], ti = z[(size_t)tn*2+1];
    float rr = rel[2*r], ri = rel[2*r+1];
    out[tid] = hr*rr*tr + hi*rr*ti + hr*ri*ti - hi*ri*tr;
}

extern "C" void kernel_launch(void* const* d_in, const int* in_sizes, int n_in,
                              void* d_out, int out_size, void* d_ws, size_t ws_size,
                              hipStream_t stream)
{
    const float* x      = (const float*)d_in[0];
    const int*   ei     = (const int*)d_in[1];
    const int*   eli    = (const int*)d_in[2];
    const float* past1  = (const float*)d_in[3];
    const float* past2  = (const float*)d_in[4];
    const float* W1rel  = (const float*)d_in[5];
    const float* b1rel  = (const float*)d_in[6];
    const float* W1root = (const float*)d_in[7];
    const float* g1Wi   = (const float*)d_in[8];
    const float* g1Wh   = (const float*)d_in[9];
    const float* g1bi   = (const float*)d_in[10];
    const float* g1bh   = (const float*)d_in[11];
    const float* k1W    = (const float*)d_in[12];
    const float* k1b    = (const float*)d_in[13];
    const float* q1     = (const float*)d_in[14];
    const float* W2rel  = (const float*)d_in[15];
    const float* b2rel  = (const float*)d_in[16];
    const float* W2root = (const float*)d_in[17];
    const float* g2Wi   = (const float*)d_in[18];
    const float* g2Wh   = (const float*)d_in[19];
    const float* g2bi   = (const float*)d_in[20];
    const float* g2bh   = (const float*)d_in[21];
    const float* k2W    = (const float*)d_in[22];
    const float* k2b    = (const float*)d_in[23];
    const float* q2     = (const float*)d_in[24];
    const float* postW  = (const float*)d_in[25];
    const float* postb  = (const float*)d_in[26];
    const float* rel    = (const float*)d_in[27];

    // ---- workspace layout (39.6 MB) ----
    char* ws = (char*)d_ws;
    float* scoreS = (float*)ws;                         // header: 6 floats
    int*   cursor = (int*)(ws + 128);                   // CSR global cursor
    float* z      = (float*)(ws + 256);                 // 800,000 B
    u16*   xbf    = (u16*)  (ws + 800256);              // N*64 bf16 = 12.8 MB (asem aliases)
    int*   deg    = (int*)  (ws + 13600256);            // 3*N ints = 1.2 MB
    int*   baseA  = (int*)  (ws + 14800256);            // 3*N ints
    int*   curA   = (int*)  (ws + 16000256);            // 3*N ints
    unsigned int* slots = (unsigned int*)(ws + 17200256); // 3*E u32 = 9.6 MB
    u16*   aggbf  = (u16*)  (ws + 26800256);            // N*64 bf16 = 12.8 MB (per-rel reuse)
    const size_t WS_NEED = 26800256 + (size_t)N_NODES*64*2;   // 39,600,256 B
    if (ws_size < WS_NEED) return;

    u16* asem = xbf;   // layer-2 node features overwrite xbf (all xbf readers done)

    // outputs are FLOAT32: scores | cur1 | cur2
    float* out  = (float*)d_out;
    float* cur1 = out + 600000;
    float* cur2 = cur1 + (size_t)R_REL*N_NODES*64;

    hipMemsetAsync(ws, 0, 256, stream);                    // scoreS + cursor
    hipMemsetAsync(deg, 0, 3*N_NODES*sizeof(int), stream);

    k_tobf<<<N_NODES*64/8/256, 256, 0, stream>>>(x, xbf, N_NODES*64/8);

    // CSR built once, reused by both layers
    k_hist3<<<HGB, 256, 0, stream>>>(ei, deg);
    k_base3<<<BGB, 256, 0, stream>>>(deg, baseA, curA, cursor);
    k_fill3<<<HGB, 256, 0, stream>>>(ei, curA, slots);

    const size_t RS = (size_t)N_NODES*64;   // per-relation slice (elems)

    // ---- layer 1 ----
    for (int r = 0; r < R_REL; ++r){
        k_agg<<<AGB, 256, 0, stream>>>(deg + r*N_NODES, baseA + r*N_NODES, slots,
                                       xbf, aggbf);
        k_densegru<<<DGB, 256, 0, stream>>>(aggbf, xbf,
                                            W1rel + r*4096, b1rel + r*64, W1root + r*4096,
                                            g1Wi, g1Wh, g1bi, g1bh,
                                            past1 + r*RS, cur1 + r*RS);
    }
    k_att<<<R_REL*ABPR, 256, 0, stream>>>(cur1, k1W, k1b, q1, scoreS);
    k_combine1<<<(N_NODES*64/8)/256, 256, 0, stream>>>(scoreS, cur1, asem);

    // ---- layer 2 ----
    for (int r = 0; r < R_REL; ++r){
        k_agg<<<AGB, 256, 0, stream>>>(deg + r*N_NODES, baseA + r*N_NODES, slots,
                                       asem, aggbf);
        k_densegru<<<DGB, 256, 0, stream>>>(aggbf, asem,
                                            W2rel + r*4096, b2rel + r*64, W2root + r*4096,
                                            g2Wi, g2Wh, g2bi, g2bh,
                                            past2 + r*RS, cur2 + r*RS);
    }
    k_att<<<R_REL*ABPR, 256, 0, stream>>>(cur2, k2W, k2b, q2, scoreS + 3);
    k_combine2z<<<(N_NODES*64)/256, 256, 0, stream>>>(scoreS + 3, cur2, postW, postb, z);

    // ---- edge scores ----
    k_score<<<(R_REL*L_EDGES + 255)/256, 256, 0, stream>>>(eli, z, rel, out);
}